// Round 1
// baseline (169.122 us; speedup 1.0000x reference)
//
#include <hip/hip_runtime.h>
#include <math.h>

// DecomposedFrequencyLearning: NaN-fill -> rfft(4096) -> 4x freq mask -> irfft
// x[32,4096,64] f32  ->  out[4,32,4096,64] f32
//
// Strategy: one workgroup per (batch, channel-pair). Two real channels packed
// as one complex series; real symmetric mask commutes with Hermitian split.
// Radix-4 DIF forward (natural->digit-reversed), mask in digit-reversed order,
// radix-4 DIT inverse (digit-reversed->natural). Spectrum held in registers
// across the 4 filters.

namespace {

constexpr int NFFT = 4096;
constexpr int NTHREADS = 256;
constexpr int VPT = NFFT / NTHREADS;   // 16 complex values per thread
constexpr int NB = 32;                 // batch
constexpr int NC = 64;                 // channels
constexpr int KF = 4;                  // filters

__device__ __forceinline__ int pad(int i) { return i + (i >> 4); }

__device__ __forceinline__ float2 cadd(float2 a, float2 b) {
    return make_float2(a.x + b.x, a.y + b.y);
}
__device__ __forceinline__ float2 csub(float2 a, float2 b) {
    return make_float2(a.x - b.x, a.y - b.y);
}
__device__ __forceinline__ float2 cmul(float2 a, float2 b) {
    return make_float2(a.x * b.x - a.y * b.y, a.x * b.y + a.y * b.x);
}
// a * conj(b)
__device__ __forceinline__ float2 cmulc(float2 a, float2 b) {
    return make_float2(a.x * b.x + a.y * b.y, a.y * b.x - a.x * b.y);
}

__global__ __launch_bounds__(NTHREADS)
void dfl_kernel(const float* __restrict__ x,
                const int* __restrict__ taus,
                const int* __restrict__ mus,
                float* __restrict__ out)
{
    __shared__ float2 buf[NFFT + NFFT / 16];   // padded: 4352 * 8B = 34816B
    __shared__ float2 wtab[1024];              // exp(-2*pi*i*j/4096), j<1024
    __shared__ float2 chLast[NTHREADS];
    __shared__ float2 chFirst[NTHREADS];

    const int tid = threadIdx.x;
    // XCD-chunked swizzle: 1024 blocks = 8 XCDs * 128. Blocks sharing a batch
    // (32 consecutive logical ids) land on the same XCD for L2 line merging.
    const int l = ((blockIdx.x & 7) << 7) | (blockIdx.x >> 3);
    const int b = l >> 5;          // batch index
    const int p = l & 31;          // channel pair
    const int c0 = p << 1;

    const float QNAN = __uint_as_float(0x7fc00000u);

    // ---- twiddle table (accurate sincos, once) ----
    for (int j = tid; j < 1024; j += NTHREADS) {
        float s, c;
        float ang = -3.14159265358979323846f * (float)j / 2048.0f;
        sincosf(ang, &s, &c);
        wtab[j] = make_float2(c, s);
    }

    // w(k) for k in [0, 3072): quadrant fold of wtab
    auto tw = [&](int k) -> float2 {
        float2 w = wtab[k & 1023];
        int qq = k >> 10;
        if (qq == 1) w = make_float2(w.y, -w.x);        // * -i
        else if (qq == 2) w = make_float2(-w.x, -w.y);  // * -1
        return w;
    };

    // ---- load + NaN fill (forward fill; leading NaNs -> first obs; all-NaN -> 0)
    const float* xb = x + ((size_t)b * NFFT) * NC + c0;
    const int base = tid * VPT;
    float2 last = make_float2(QNAN, QNAN);
    float2 first = make_float2(QNAN, QNAN);
    float2 vals[VPT];
    for (int j = 0; j < VPT; ++j) {
        float2 v = *reinterpret_cast<const float2*>(xb + (size_t)(base + j) * NC);
        if (first.x != first.x && v.x == v.x) first.x = v.x;
        if (first.y != first.y && v.y == v.y) first.y = v.y;
        if (v.x == v.x) last.x = v.x; else v.x = last.x;   // fwd fill in chunk
        if (v.y == v.y) last.y = v.y; else v.y = last.y;
        vals[j] = v;                                       // NaN only in leading run
    }
    chLast[tid] = last;
    chFirst[tid] = first;
    __syncthreads();

    // last observed value in any chunk before this one (nearest first)
    float2 pre = make_float2(QNAN, QNAN);
    for (int k = tid - 1; k >= 0; --k) {
        float2 s2 = chLast[k];
        if (pre.x != pre.x) pre.x = s2.x;
        if (pre.y != pre.y) pre.y = s2.y;
        if (pre.x == pre.x && pre.y == pre.y) break;
    }
    // globally first observed value (for the leading-NaN prefix)
    float2 gfirst = make_float2(QNAN, QNAN);
    for (int k = 0; k < NTHREADS; ++k) {
        float2 s2 = chFirst[k];
        if (gfirst.x != gfirst.x) gfirst.x = s2.x;
        if (gfirst.y != gfirst.y) gfirst.y = s2.y;
    }
    if (gfirst.x != gfirst.x) gfirst.x = 0.0f;   // all-NaN series -> 0
    if (gfirst.y != gfirst.y) gfirst.y = 0.0f;
    const float fillx = (pre.x == pre.x) ? pre.x : gfirst.x;
    const float filly = (pre.y == pre.y) ? pre.y : gfirst.y;
    for (int j = 0; j < VPT; ++j) {
        float2 v = vals[j];
        if (v.x != v.x) v.x = fillx;
        if (v.y != v.y) v.y = filly;
        buf[pad(base + j)] = v;
    }
    __syncthreads();

    // ---- forward radix-4 DIF FFT: natural -> base-4 digit-reversed ----
    for (int st = 0; st < 6; ++st) {
        const int lq = 10 - 2 * st;          // log2(q)
        const int q = 1 << lq;               // len/4
        const int step = 1 << (2 * st);      // NFFT/len
        for (int it = 0; it < 4; ++it) {
            const int m = tid + NTHREADS * it;       // butterfly id, 0..1023
            const int j = m & (q - 1);
            const int i0 = ((m >> lq) << (lq + 2)) + j;
            float2 u0 = buf[pad(i0)];
            float2 u1 = buf[pad(i0 + q)];
            float2 u2 = buf[pad(i0 + 2 * q)];
            float2 u3 = buf[pad(i0 + 3 * q)];
            float2 t0 = cadd(u0, u2), t1 = csub(u0, u2);
            float2 t2 = cadd(u1, u3), t3 = csub(u1, u3);
            float2 mi3 = make_float2(t3.y, -t3.x);   // -i * t3
            float2 b0 = cadd(t0, t2);
            float2 b1 = cadd(t1, mi3);
            float2 b2 = csub(t0, t2);
            float2 b3 = csub(t1, mi3);
            const int k1 = j * step;
            if (k1) {                                  // st==0 has k1==j*1 ... keep general
                b1 = cmul(b1, tw(k1));
                b2 = cmul(b2, tw(2 * k1));
                b3 = cmul(b3, tw(3 * k1));
            }
            buf[pad(i0)]         = b0;
            buf[pad(i0 + q)]     = b1;
            buf[pad(i0 + 2 * q)] = b2;
            buf[pad(i0 + 3 * q)] = b3;
        }
        __syncthreads();
    }

    // ---- park spectrum in registers; rfft freq index per slot ----
    float2 spec[VPT];
    int freqs[VPT];
    for (int j = 0; j < VPT; ++j) {
        spec[j] = buf[pad(base + j)];
        int s = base + j, r = 0;
        for (int d = 0; d < 6; ++d) { r = (r << 2) | (s & 3); s >>= 2; }
        freqs[j] = (r <= NFFT / 2) ? r : (NFFT - r);
    }

    // ---- per filter: mask -> inverse FFT -> write ----
    const float scale = 1.0f / (float)NFFT;
    for (int k = 0; k < KF; ++k) {
        const int tau = taus[k];
        const int mu = mus[k];
        for (int j = 0; j < VPT; ++j) {
            const bool keep = (mu == 1) ? (freqs[j] < tau) : (freqs[j] >= tau);
            buf[pad(base + j)] = keep ? spec[j] : make_float2(0.0f, 0.0f);
        }
        __syncthreads();

        // inverse radix-4 DIT: digit-reversed -> natural (unscaled, x NFFT)
        for (int st = 0; st < 6; ++st) {
            const int lq = 2 * st;
            const int q = 1 << lq;
            const int step = 1024 >> (2 * st);
            for (int it = 0; it < 4; ++it) {
                const int m = tid + NTHREADS * it;
                const int j2 = m & (q - 1);
                const int i0 = ((m >> lq) << (lq + 2)) + j2;
                float2 c0v = buf[pad(i0)];
                float2 c1 = buf[pad(i0 + q)];
                float2 c2 = buf[pad(i0 + 2 * q)];
                float2 c3 = buf[pad(i0 + 3 * q)];
                const int k1 = j2 * step;
                if (k1) {
                    c1 = cmulc(c1, tw(k1));
                    c2 = cmulc(c2, tw(2 * k1));
                    c3 = cmulc(c3, tw(3 * k1));
                }
                float2 t0 = cadd(c0v, c2), t1 = csub(c0v, c2);
                float2 t2 = cadd(c1, c3),  t3 = csub(c1, c3);
                float2 i3 = make_float2(-t3.y, t3.x);    // +i * t3
                buf[pad(i0)]         = cadd(t0, t2);
                buf[pad(i0 + q)]     = cadd(t1, i3);
                buf[pad(i0 + 2 * q)] = csub(t0, t2);
                buf[pad(i0 + 3 * q)] = csub(t1, i3);
            }
            __syncthreads();
        }

        // write: out[k][b][t][c0..c0+1], lanes cover consecutive t
        float* ob = out + (((size_t)(k * NB + b)) * NFFT) * NC + c0;
        for (int jt = 0; jt < VPT; ++jt) {
            const int t = tid + NTHREADS * jt;
            float2 v = buf[pad(t)];
            *reinterpret_cast<float2*>(ob + (size_t)t * NC) =
                make_float2(v.x * scale, v.y * scale);
        }
        __syncthreads();   // protect buf before next filter's mask-copy
    }
}

} // namespace

extern "C" void kernel_launch(void* const* d_in, const int* in_sizes, int n_in,
                              void* d_out, int out_size, void* d_ws, size_t ws_size,
                              hipStream_t stream) {
    const float* x   = (const float*)d_in[0];
    const int* taus  = (const int*)d_in[1];
    const int* mus   = (const int*)d_in[2];
    float* out       = (float*)d_out;
    dfl_kernel<<<dim3(NB * NC / 2), dim3(NTHREADS), 0, stream>>>(x, taus, mus, out);
}